// Round 12
// baseline (41.822 us; speedup 1.0000x reference)
//
#include <hip/hip_runtime.h>
#include <hip/hip_fp16.h>
#include <math.h>

// Problem constants (fixed by reference setup_inputs): x [2,3,512,512] f32.
#define BC 6
#define H_ 512
#define W_ 512
#define HW (H_ * W_)
#define EPS 1e-6f
#define EXPM05 0.60653065971263342f  // exp(-0.5)

#define TW 72    // tile cols (64 outputs + 8 halo)
#define TH 24    // tile rows (16 outputs + 8 halo)
#define XSS 26   // xs column stride (even -> 8B-aligned b64 reads in E; gcd(26,32)=2)

// Block 64x8 = 512 threads -> 64x16 output tile. 35.1 KB LDS; 4 blocks/CU.
// vh row-pair index == ty: wave ty PRODUCES and CONSUMES only vh[..][ty][..]
// -> B->D sync is wave-local (s_waitcnt lgkmcnt(0); same-wave DS ops execute
// in order). ONE __syncthreads in the whole kernel (after staging).
//  A: stage xs (p).                                            [barrier]
//  B: wave-local row-pair units (unit0 col=tx; unit1 col=64+tx, tx<8):
//     running vertical sums for both rows (10 reads + 10 logs per 2 rows),
//     publish all R as packed half2.                           [lgkmcnt(0)]
//  D: per R: (R+1) aligned ds_read_b64 per stat + hadd2 reduce + parity
//     fix; contrast/energy/entropy out (nontemporal); keep means.
//  E: homogeneity pass (non-separable) from xs; nontemporal store.
// NOTE: no min-occupancy arg in launch_bounds — rounds 4/5 proved it forces
// VGPR=40 + catastrophic scratch spill (FETCH 70-117 MB vs ~6 MB clean).
__global__ __launch_bounds__(512) void texmart_kernel(const float* __restrict__ x,
                                                      float* __restrict__ out) {
    __shared__ float xs[TW][XSS];       // 7488 B  [col][row]
    __shared__ __half2 vh[12][8][72];   // 27648 B [stat*4+R-1][opair][col] (lo=even o, hi=odd o)

    const int tx = threadIdx.x, ty = threadIdx.y;
    const int tid = ty * 64 + tx;
    const int bx = blockIdx.x * 64, by = blockIdx.y * 16;
    const int plane = blockIdx.z;
    const float* __restrict__ xp = x + (size_t)plane * HW;

    // ---------------- A: stage tile (zero pad) ----------------
    for (int idx = tid; idx < TW * TH; idx += 512) {
        const int t = idx / TW, c = idx - t * TW;
        const int gy = by + t - 4, gx = bx + c - 4;
        float v = 0.f;
        if (gy >= 0 && gy < H_ && gx >= 0 && gx < W_) v = xp[gy * W_ + gx];
        xs[c][t] = v;
    }
    __syncthreads();

    // ---------------- B: wave-local row-pair vertical running sums ----------------
    // Wave ty fills vh[..][ty][0..71]: unit0 col=tx (all lanes), unit1 col=64+tx (tx<8).
#pragma unroll
    for (int i = 0; i < 2; ++i) {
        if (i == 0 || tx < 8) {
            const int c = (i == 0) ? tx : (64 + tx);
            const int op = ty;
            const float* __restrict__ col = &xs[c][0];
            const float pA = col[2 * op + 4];     // center row of even output row
            const float pB = col[2 * op + 5];     // center row of odd output row
            const float qA = pA * __logf(pA + EPS);
            const float qB = pB * __logf(pB + EPS);
            float s1a = pA, s2a = pA * pA, sla = qA;
            float s1b = pB, s2b = pB * pB, slb = qB;
            float lop = pA, hip = pB, qlop = qA, qhip = qB;   // lo_{R-1}, hi_{R-1}
#pragma unroll
            for (int R = 1; R <= 4; ++R) {
                const float lo = col[2 * op + 4 - R];
                const float hi = col[2 * op + 5 + R];
                const float qlo = lo * __logf(lo + EPS);      // zero-pad -> exactly 0
                const float qhi = hi * __logf(hi + EPS);
                // row A window rows [2op+4-R, 2op+4+R]; row 2op+4+R == hi_{R-1}
                s1a += lo + hip;
                s2a = __fmaf_rn(lo, lo, __fmaf_rn(hip, hip, s2a));
                sla += qlo + qhip;
                // row B window rows [2op+5-R, 2op+5+R]; row 2op+5-R == lo_{R-1}
                s1b += lop + hi;
                s2b = __fmaf_rn(lop, lop, __fmaf_rn(hi, hi, s2b));
                slb += qlop + qhi;
                vh[0 * 4 + R - 1][op][c] = __float22half2_rn(make_float2(s1a, s1b));
                vh[1 * 4 + R - 1][op][c] = __float22half2_rn(make_float2(s2a, s2b));
                vh[2 * 4 + R - 1][op][c] = __float22half2_rn(make_float2(sla, slb));
                lop = lo; hip = hi; qlop = qlo; qhip = qhi;
            }
        }
    }
    // Wave-local B->D dependency: drain this wave's DS queue; same-wave DS ops
    // execute in order, and vh row ty is private to wave ty -> no __syncthreads.
    asm volatile("s_waitcnt lgkmcnt(0)" ::: "memory");

    // ---------------- D: per-R horizontal sums via aligned b64 + parity fix ----------------
    float mean[2][4];
    const int gxx = bx + tx;
    float* __restrict__ obase = out + (size_t)plane * 16 * HW + (size_t)by * W_ + gxx;

#pragma unroll
    for (int R = 1; R <= 4; ++R) {
        // span words [tx+4-R, tx+4+R]; aligned start a (even) -> R+1 b64 loads
        // cover words a..a+2R+1 = span plus ONE surplus column (front if
        // tx+4-R odd, else back). Sum all, subtract surplus.
        const int a = (tx + 4 - R) & ~1;
        const bool frontX = ((tx + 4 - R) & 1) != 0;
        __half2 S[3];
#pragma unroll
        for (int st = 0; st < 3; ++st) {
            const __half2* __restrict__ row = &vh[st * 4 + (R - 1)][ty][0];
            __half2 acc = __float2half2_rn(0.f);
            __half2 first = __float2half2_rn(0.f), last = __float2half2_rn(0.f);
#pragma unroll
            for (int k = 0; k <= R; ++k) {
                const uint2 u = *(const uint2*)&row[a + 2 * k];   // ds_read_b64
                const __half2 lo = *(const __half2*)&u.x;
                const __half2 hi = *(const __half2*)&u.y;
                if (k == 0) first = lo;
                if (k == R) last = hi;
                acc = __hadd2(acc, __hadd2(lo, hi));
            }
            S[st] = __hsub2(acc, frontX ? first : last);
        }
        const float S1v[2] = {__low2float(S[0]), __high2float(S[0])};
        const float S2v[2] = {__low2float(S[1]), __high2float(S[1])};
        const float SLv[2] = {__low2float(S[2]), __high2float(S[2])};

        const float K = (float)((2 * R + 1) * (2 * R + 1));
        const float invK = 1.f / K;
        const float invKm1 = 1.f / (K - 1.f);
#pragma unroll
        for (int oi = 0; oi < 2; ++oi) {
            const int o = ty * 2 + oi;
            const float m = S1v[oi] * invK;
            mean[oi][R - 1] = m;
            float S2c = __fmaf_rn(-S1v[oi], m, S2v[oi]);   // Σ(p-mean)^2
            if (S2c < 0.f) S2c = 0.f;
            const float sd = sqrtf(S2c * invKm1) + EPS;    // ddof=1 std + EPS
            const float contrast = (S2c * invK) * __frcp_rn(sd * sd);
            const float energy = S2v[oi] * invK;
            const float entropy = -SLv[oi] * invK;

            float* __restrict__ o4 = obase + o * W_ + (R - 1) * 4 * HW;
            __builtin_nontemporal_store((contrast + EPS) * EXPM05, &o4[0 * HW]);
            __builtin_nontemporal_store((energy + EPS) * EXPM05, &o4[1 * HW]);
            __builtin_nontemporal_store((entropy + EPS) * EXPM05, &o4[2 * HW]);
        }
    }

    // ---------------- E: homogeneity (reads xs only; xs stable since A) ----------------
    const int ty2 = ty * 2;
    float sa[2][4];
#pragma unroll
    for (int oi = 0; oi < 2; ++oi)
#pragma unroll
        for (int R = 0; R < 4; ++R) sa[oi][R] = 0.f;

#pragma unroll
    for (int dj = 0; dj < 9; ++dj) {
        const int a = dj < 4 ? 4 - dj : dj - 4;
        const float* __restrict__ col = &xs[tx + dj][ty2];
        const float2 u0 = *(const float2*)(col + 0);
        const float2 u1 = *(const float2*)(col + 2);
        const float2 u2 = *(const float2*)(col + 4);
        const float2 u3 = *(const float2*)(col + 6);
        const float2 u4 = *(const float2*)(col + 8);
        const float p[10] = {u0.x, u0.y, u1.x, u1.y, u2.x, u2.y, u3.x, u3.y, u4.x, u4.y};

#pragma unroll
        for (int oi = 0; oi < 2; ++oi) {
#pragma unroll
            for (int k = 0; k < 9; ++k) {
                const int adi = k < 4 ? 4 - k : k - 4;
                const int rm = a > adi ? a : adi;
                const int r0 = rm < 1 ? 1 : rm;           // compile-time
#pragma unroll
                for (int R = 1; R <= 4; ++R) {
                    if (R >= r0) sa[oi][R - 1] += fabsf(p[oi + k] - mean[oi][R - 1]);
                }
            }
        }
    }

#pragma unroll
    for (int oi = 0; oi < 2; ++oi) {
        const int o = ty2 + oi;
#pragma unroll
        for (int R = 1; R <= 4; ++R) {
            const float K = (float)((2 * R + 1) * (2 * R + 1));
            const float homog = __frcp_rn(1.f + sa[oi][R - 1] * (1.f / K));
            __builtin_nontemporal_store((homog + EPS) * EXPM05,
                                        &obase[o * W_ + (R - 1) * 4 * HW + 3 * HW]);
        }
    }
}

extern "C" void kernel_launch(void* const* d_in, const int* in_sizes, int n_in,
                              void* d_out, int out_size, void* d_ws, size_t ws_size,
                              hipStream_t stream) {
    const float* x = (const float*)d_in[0];
    float* out = (float*)d_out;
    dim3 block(64, 8, 1);
    dim3 grid(W_ / 64, H_ / 16, BC);
    texmart_kernel<<<grid, block, 0, stream>>>(x, out);
}

// Round 13
// 38.792 us; speedup vs baseline: 1.0781x; 1.0781x over previous
//
#include <hip/hip_runtime.h>
#include <hip/hip_fp16.h>
#include <math.h>

// Problem constants (fixed by reference setup_inputs): x [2,3,512,512] f32.
#define BC 6
#define H_ 512
#define W_ 512
#define HW (H_ * W_)
#define EPS 1e-6f
#define EXPM05 0.60653065971263342f  // exp(-0.5)

#define TW 72    // tile cols (64 outputs + 8 halo)
#define TH 24    // tile rows (16 outputs + 8 halo)
#define XSS 26   // xs column stride (even -> 8B-aligned b64/float2; gcd(26,32)=2)
#define XES 14   // xe column stride in uints (even)

static __device__ __forceinline__ __half2 habs2(__half2 v) {
    unsigned int u;
    __builtin_memcpy(&u, &v, 4);
    u &= 0x7FFF7FFFu;
    __half2 r;
    __builtin_memcpy(&r, &u, 4);
    return r;
}

// Block 64x8 = 512 threads -> 64x16 output tile. 39.2 KB LDS; 4 blocks/CU.
//  A : stage xs (p, f32).                                      [barrier]
//  A2: stage xe[c][t] = half2(row 2t, row 2t+1) from xs (864 units).
//  B : 576 row-pair units; running vertical sums for both rows (10 reads +
//      10 logs per 2 rows), publish all R as packed half2 vh.  [barrier]
//  D : per R: (R+1) aligned ds_read_b64 per stat + hadd2 reduce + parity
//      fix; contrast/energy/entropy out (nontemporal); keep means.
//  E : homogeneity fully f16-packed along the two output rows: 3 DS instr
//      per column (ds_read2_b32), pk_sub/and/pk_add per contribution.
// NOTE: no min-occupancy arg in launch_bounds — rounds 4/5 proved it forces
// VGPR=40 + catastrophic scratch spill (FETCH 70-117 MB vs ~6 MB clean).
__global__ __launch_bounds__(512) void texmart_kernel(const float* __restrict__ x,
                                                      float* __restrict__ out) {
    __shared__ float xs[TW][XSS];         // 7488 B  [col][row]
    __shared__ __half2 vh[12][8][72];     // 27648 B [stat*4+R-1][opair][col]
    __shared__ unsigned int xe[TW][XES];  // 4032 B  [col][rowpair] packed half2

    const int tx = threadIdx.x, ty = threadIdx.y;
    const int tid = ty * 64 + tx;
    const int bx = blockIdx.x * 64, by = blockIdx.y * 16;
    const int plane = blockIdx.z;
    const float* __restrict__ xp = x + (size_t)plane * HW;

    // ---------------- A: stage tile (zero pad) ----------------
    for (int idx = tid; idx < TW * TH; idx += 512) {
        const int t = idx / TW, c = idx - t * TW;
        const int gy = by + t - 4, gx = bx + c - 4;
        float v = 0.f;
        if (gy >= 0 && gy < H_ && gx >= 0 && gx < W_) v = xp[gy * W_ + gx];
        xs[c][t] = v;
    }
    __syncthreads();

    // ---------------- A2: pack row-pairs to f16 for E (864 units) ----------------
    for (int u = tid; u < TW * 12; u += 512) {
        const int c = u % TW, t = u / TW;          // t = row pair 0..11
        const float2 pp = *(const float2*)&xs[c][2 * t];
        const __half2 h = __float22half2_rn(make_float2(pp.x, pp.y));
        unsigned int bits;
        __builtin_memcpy(&bits, &h, 4);
        xe[c][t] = bits;
    }

    // ---------------- B: row-pair vertical running sums, publish all R ----------------
#pragma unroll
    for (int i = 0; i < 2; ++i) {
        if (i == 0 || tid < 64) {            // unit 512+tid handled by wave 0 only
            const int u = tid + i * 512;     // < 576 under guard
            const int op = u / 72, c = u - (u / 72) * 72;
            const float* __restrict__ col = &xs[c][0];
            const float pA = col[2 * op + 4];     // center row of even output row
            const float pB = col[2 * op + 5];     // center row of odd output row
            const float qA = pA * __logf(pA + EPS);
            const float qB = pB * __logf(pB + EPS);
            float s1a = pA, s2a = pA * pA, sla = qA;
            float s1b = pB, s2b = pB * pB, slb = qB;
            float lop = pA, hip = pB, qlop = qA, qhip = qB;   // lo_{R-1}, hi_{R-1}
#pragma unroll
            for (int R = 1; R <= 4; ++R) {
                const float lo = col[2 * op + 4 - R];
                const float hi = col[2 * op + 5 + R];
                const float qlo = lo * __logf(lo + EPS);      // zero-pad -> exactly 0
                const float qhi = hi * __logf(hi + EPS);
                // row A window rows [2op+4-R, 2op+4+R]; row 2op+4+R == hi_{R-1}
                s1a += lo + hip;
                s2a = __fmaf_rn(lo, lo, __fmaf_rn(hip, hip, s2a));
                sla += qlo + qhip;
                // row B window rows [2op+5-R, 2op+5+R]; row 2op+5-R == lo_{R-1}
                s1b += lop + hi;
                s2b = __fmaf_rn(lop, lop, __fmaf_rn(hi, hi, s2b));
                slb += qlop + qhi;
                vh[0 * 4 + R - 1][op][c] = __float22half2_rn(make_float2(s1a, s1b));
                vh[1 * 4 + R - 1][op][c] = __float22half2_rn(make_float2(s2a, s2b));
                vh[2 * 4 + R - 1][op][c] = __float22half2_rn(make_float2(sla, slb));
                lop = lo; hip = hi; qlop = qlo; qhip = qhi;
            }
        }
    }
    __syncthreads();

    // ---------------- D: per-R horizontal sums via aligned b64 + parity fix ----------------
    float mean[2][4];
    const int gxx = bx + tx;
    float* __restrict__ obase = out + (size_t)plane * 16 * HW + (size_t)by * W_ + gxx;

#pragma unroll
    for (int R = 1; R <= 4; ++R) {
        // span words [tx+4-R, tx+4+R]; aligned start a (even) -> R+1 b64 loads
        // cover span plus ONE surplus column (front if tx+4-R odd, else back).
        const int a = (tx + 4 - R) & ~1;
        const bool frontX = ((tx + 4 - R) & 1) != 0;
        __half2 S[3];
#pragma unroll
        for (int st = 0; st < 3; ++st) {
            const __half2* __restrict__ row = &vh[st * 4 + (R - 1)][ty][0];
            __half2 acc = __float2half2_rn(0.f);
            __half2 first = __float2half2_rn(0.f), last = __float2half2_rn(0.f);
#pragma unroll
            for (int k = 0; k <= R; ++k) {
                const uint2 u = *(const uint2*)&row[a + 2 * k];   // ds_read_b64
                const __half2 lo = *(const __half2*)&u.x;
                const __half2 hi = *(const __half2*)&u.y;
                if (k == 0) first = lo;
                if (k == R) last = hi;
                acc = __hadd2(acc, __hadd2(lo, hi));
            }
            S[st] = __hsub2(acc, frontX ? first : last);
        }
        const float S1v[2] = {__low2float(S[0]), __high2float(S[0])};
        const float S2v[2] = {__low2float(S[1]), __high2float(S[1])};
        const float SLv[2] = {__low2float(S[2]), __high2float(S[2])};

        const float K = (float)((2 * R + 1) * (2 * R + 1));
        const float invK = 1.f / K;
        const float invKm1 = 1.f / (K - 1.f);
#pragma unroll
        for (int oi = 0; oi < 2; ++oi) {
            const int o = ty * 2 + oi;
            const float m = S1v[oi] * invK;
            mean[oi][R - 1] = m;
            float S2c = __fmaf_rn(-S1v[oi], m, S2v[oi]);   // Σ(p-mean)^2
            if (S2c < 0.f) S2c = 0.f;
            const float sd = sqrtf(S2c * invKm1) + EPS;    // ddof=1 std + EPS
            const float contrast = (S2c * invK) * __frcp_rn(sd * sd);
            const float energy = S2v[oi] * invK;
            const float entropy = -SLv[oi] * invK;

            float* __restrict__ o4 = obase + o * W_ + (R - 1) * 4 * HW;
            __builtin_nontemporal_store((contrast + EPS) * EXPM05, &o4[0 * HW]);
            __builtin_nontemporal_store((energy + EPS) * EXPM05, &o4[1 * HW]);
            __builtin_nontemporal_store((entropy + EPS) * EXPM05, &o4[2 * HW]);
        }
    }

    // ---------------- E: homogeneity, f16-packed along (o, o+1) ----------------
    // q[k] = half2(p_row[ty2+k], p_row[ty2+k+1]) -> both pixels' element k.
    __half2 m2[4];
#pragma unroll
    for (int R = 0; R < 4; ++R)
        m2[R] = __float22half2_rn(make_float2(mean[0][R], mean[1][R]));

    __half2 sa2[4];
#pragma unroll
    for (int R = 0; R < 4; ++R) sa2[R] = __float2half2_rn(0.f);

#pragma unroll
    for (int dj = 0; dj < 9; ++dj) {
        const int a = dj < 4 ? 4 - dj : dj - 4;
        const unsigned int* __restrict__ col = &xe[tx + dj][ty];  // pairs ty..ty+4
        const unsigned int w0 = col[0], w1 = col[1], w2 = col[2], w3 = col[3], w4 = col[4];
        unsigned int qu[9];
        qu[0] = w0; qu[2] = w1; qu[4] = w2; qu[6] = w3; qu[8] = w4;
        qu[1] = (w0 >> 16) | (w1 << 16);   // v_alignbit
        qu[3] = (w1 >> 16) | (w2 << 16);
        qu[5] = (w2 >> 16) | (w3 << 16);
        qu[7] = (w3 >> 16) | (w4 << 16);

#pragma unroll
        for (int k = 0; k < 9; ++k) {
            const int adi = k < 4 ? 4 - k : k - 4;
            const int rm = a > adi ? a : adi;
            const int r0 = rm < 1 ? 1 : rm;           // compile-time
            __half2 qk;
            __builtin_memcpy(&qk, &qu[k], 4);
#pragma unroll
            for (int R = 1; R <= 4; ++R) {
                if (R >= r0)
                    sa2[R - 1] = __hadd2(sa2[R - 1], habs2(__hsub2(qk, m2[R - 1])));
            }
        }
    }

#pragma unroll
    for (int oi = 0; oi < 2; ++oi) {
        const int o = ty * 2 + oi;
#pragma unroll
        for (int R = 1; R <= 4; ++R) {
            const float K = (float)((2 * R + 1) * (2 * R + 1));
            const float sav = oi ? __high2float(sa2[R - 1]) : __low2float(sa2[R - 1]);
            const float homog = __frcp_rn(1.f + sav * (1.f / K));
            __builtin_nontemporal_store((homog + EPS) * EXPM05,
                                        &obase[o * W_ + (R - 1) * 4 * HW + 3 * HW]);
        }
    }
}

extern "C" void kernel_launch(void* const* d_in, const int* in_sizes, int n_in,
                              void* d_out, int out_size, void* d_ws, size_t ws_size,
                              hipStream_t stream) {
    const float* x = (const float*)d_in[0];
    float* out = (float*)d_out;
    dim3 block(64, 8, 1);
    dim3 grid(W_ / 64, H_ / 16, BC);
    texmart_kernel<<<grid, block, 0, stream>>>(x, out);
}

// Round 14
// 38.677 us; speedup vs baseline: 1.0813x; 1.0030x over previous
//
#include <hip/hip_runtime.h>
#include <hip/hip_fp16.h>
#include <math.h>

// Problem constants (fixed by reference setup_inputs): x [2,3,512,512] f32.
#define BC 6
#define H_ 512
#define W_ 512
#define HW (H_ * W_)
#define EPS 1e-6f
#define EXPM05 0.60653065971263342f  // exp(-0.5)

#define TW 72    // tile cols (64 outputs + 8 halo)
#define TH 24    // tile rows (16 outputs + 8 halo)
#define XSS 25   // xs column stride — ODD: b32 lane-bank pattern covers all 32 banks (2/bank, free)
#define XES 13   // xe column stride in uints — ODD for the same reason (was 14: 4-way conflict)

static __device__ __forceinline__ __half2 habs2(__half2 v) {
    unsigned int u;
    __builtin_memcpy(&u, &v, 4);
    u &= 0x7FFF7FFFu;
    __half2 r;
    __builtin_memcpy(&r, &u, 4);
    return r;
}

// Block 64x8 = 512 threads -> 64x16 output tile. 37.7 KB LDS; 4 blocks/CU.
//  A : stage xs (p, f32).                                      [barrier]
//  A2: stage xe[c][t] = half2(row 2t, row 2t+1) from xs (864 units).
//  B : 576 row-pair units; running vertical sums for both rows (10 reads +
//      10 logs per 2 rows), publish all R as packed half2 vh.  [barrier]
//  D : per R: (R+1) aligned ds_read_b64 per stat + hadd2 reduce + parity
//      fix; contrast/energy/entropy out (nontemporal); keep means.
//  E : homogeneity fully f16-packed along the two output rows.
// NOTE: no min-occupancy arg in launch_bounds — rounds 4/5 proved it forces
// VGPR=40 + catastrophic scratch spill (FETCH 70-117 MB vs ~6 MB clean).
__global__ __launch_bounds__(512) void texmart_kernel(const float* __restrict__ x,
                                                      float* __restrict__ out) {
    __shared__ float xs[TW][XSS];         // 7200 B  [col][row]
    __shared__ __half2 vh[12][8][72];     // 27648 B [stat*4+R-1][opair][col]
    __shared__ unsigned int xe[TW][XES];  // 3744 B  [col][rowpair] packed half2

    const int tx = threadIdx.x, ty = threadIdx.y;
    const int tid = ty * 64 + tx;
    const int bx = blockIdx.x * 64, by = blockIdx.y * 16;
    const int plane = blockIdx.z;
    const float* __restrict__ xp = x + (size_t)plane * HW;

    // ---------------- A: stage tile (zero pad) ----------------
    for (int idx = tid; idx < TW * TH; idx += 512) {
        const int t = idx / TW, c = idx - t * TW;
        const int gy = by + t - 4, gx = bx + c - 4;
        float v = 0.f;
        if (gy >= 0 && gy < H_ && gx >= 0 && gx < W_) v = xp[gy * W_ + gx];
        xs[c][t] = v;
    }
    __syncthreads();

    // ---------------- A2: pack row-pairs to f16 for E (864 units) ----------------
    // Two explicit b32 reads (NOT float2): with odd XSS, &xs[c][2t] is only
    // 4B-aligned for odd c — a b64 read would be misaligned.
    for (int u = tid; u < TW * 12; u += 512) {
        const int c = u % TW, t = u / TW;          // t = row pair 0..11
        const float p0 = xs[c][2 * t];
        const float p1 = xs[c][2 * t + 1];
        const __half2 h = __float22half2_rn(make_float2(p0, p1));
        unsigned int bits;
        __builtin_memcpy(&bits, &h, 4);
        xe[c][t] = bits;
    }

    // ---------------- B: row-pair vertical running sums, publish all R ----------------
#pragma unroll
    for (int i = 0; i < 2; ++i) {
        if (i == 0 || tid < 64) {            // unit 512+tid handled by wave 0 only
            const int u = tid + i * 512;     // < 576 under guard
            const int op = u / 72, c = u - (u / 72) * 72;
            const float* __restrict__ col = &xs[c][0];
            const float pA = col[2 * op + 4];     // center row of even output row
            const float pB = col[2 * op + 5];     // center row of odd output row
            const float qA = pA * __logf(pA + EPS);
            const float qB = pB * __logf(pB + EPS);
            float s1a = pA, s2a = pA * pA, sla = qA;
            float s1b = pB, s2b = pB * pB, slb = qB;
            float lop = pA, hip = pB, qlop = qA, qhip = qB;   // lo_{R-1}, hi_{R-1}
#pragma unroll
            for (int R = 1; R <= 4; ++R) {
                const float lo = col[2 * op + 4 - R];
                const float hi = col[2 * op + 5 + R];
                const float qlo = lo * __logf(lo + EPS);      // zero-pad -> exactly 0
                const float qhi = hi * __logf(hi + EPS);
                // row A window rows [2op+4-R, 2op+4+R]; row 2op+4+R == hi_{R-1}
                s1a += lo + hip;
                s2a = __fmaf_rn(lo, lo, __fmaf_rn(hip, hip, s2a));
                sla += qlo + qhip;
                // row B window rows [2op+5-R, 2op+5+R]; row 2op+5-R == lo_{R-1}
                s1b += lop + hi;
                s2b = __fmaf_rn(lop, lop, __fmaf_rn(hi, hi, s2b));
                slb += qlop + qhi;
                vh[0 * 4 + R - 1][op][c] = __float22half2_rn(make_float2(s1a, s1b));
                vh[1 * 4 + R - 1][op][c] = __float22half2_rn(make_float2(s2a, s2b));
                vh[2 * 4 + R - 1][op][c] = __float22half2_rn(make_float2(sla, slb));
                lop = lo; hip = hi; qlop = qlo; qhip = qhi;
            }
        }
    }
    __syncthreads();

    // ---------------- D: per-R horizontal sums via aligned b64 + parity fix ----------------
    float mean[2][4];
    const int gxx = bx + tx;
    float* __restrict__ obase = out + (size_t)plane * 16 * HW + (size_t)by * W_ + gxx;

#pragma unroll
    for (int R = 1; R <= 4; ++R) {
        // span words [tx+4-R, tx+4+R]; aligned start a (even) -> R+1 b64 loads
        // cover span plus ONE surplus column (front if tx+4-R odd, else back).
        const int a = (tx + 4 - R) & ~1;
        const bool frontX = ((tx + 4 - R) & 1) != 0;
        __half2 S[3];
#pragma unroll
        for (int st = 0; st < 3; ++st) {
            const __half2* __restrict__ row = &vh[st * 4 + (R - 1)][ty][0];
            __half2 acc = __float2half2_rn(0.f);
            __half2 first = __float2half2_rn(0.f), last = __float2half2_rn(0.f);
#pragma unroll
            for (int k = 0; k <= R; ++k) {
                const uint2 u = *(const uint2*)&row[a + 2 * k];   // ds_read_b64 (8B aligned)
                const __half2 lo = *(const __half2*)&u.x;
                const __half2 hi = *(const __half2*)&u.y;
                if (k == 0) first = lo;
                if (k == R) last = hi;
                acc = __hadd2(acc, __hadd2(lo, hi));
            }
            S[st] = __hsub2(acc, frontX ? first : last);
        }
        const float S1v[2] = {__low2float(S[0]), __high2float(S[0])};
        const float S2v[2] = {__low2float(S[1]), __high2float(S[1])};
        const float SLv[2] = {__low2float(S[2]), __high2float(S[2])};

        const float K = (float)((2 * R + 1) * (2 * R + 1));
        const float invK = 1.f / K;
        const float invKm1 = 1.f / (K - 1.f);
#pragma unroll
        for (int oi = 0; oi < 2; ++oi) {
            const int o = ty * 2 + oi;
            const float m = S1v[oi] * invK;
            mean[oi][R - 1] = m;
            float S2c = __fmaf_rn(-S1v[oi], m, S2v[oi]);   // Σ(p-mean)^2
            if (S2c < 0.f) S2c = 0.f;
            const float sd = sqrtf(S2c * invKm1) + EPS;    // ddof=1 std + EPS
            const float contrast = (S2c * invK) * __frcp_rn(sd * sd);
            const float energy = S2v[oi] * invK;
            const float entropy = -SLv[oi] * invK;

            float* __restrict__ o4 = obase + o * W_ + (R - 1) * 4 * HW;
            __builtin_nontemporal_store((contrast + EPS) * EXPM05, &o4[0 * HW]);
            __builtin_nontemporal_store((energy + EPS) * EXPM05, &o4[1 * HW]);
            __builtin_nontemporal_store((entropy + EPS) * EXPM05, &o4[2 * HW]);
        }
    }

    // ---------------- E: homogeneity, f16-packed along (o, o+1) ----------------
    __half2 m2[4];
#pragma unroll
    for (int R = 0; R < 4; ++R)
        m2[R] = __float22half2_rn(make_float2(mean[0][R], mean[1][R]));

    __half2 sa2[4];
#pragma unroll
    for (int R = 0; R < 4; ++R) sa2[R] = __float2half2_rn(0.f);

#pragma unroll
    for (int dj = 0; dj < 9; ++dj) {
        const int a = dj < 4 ? 4 - dj : dj - 4;
        const unsigned int* __restrict__ col = &xe[tx + dj][ty];  // pairs ty..ty+4
        const unsigned int w0 = col[0], w1 = col[1], w2 = col[2], w3 = col[3], w4 = col[4];
        unsigned int qu[9];
        qu[0] = w0; qu[2] = w1; qu[4] = w2; qu[6] = w3; qu[8] = w4;
        qu[1] = (w0 >> 16) | (w1 << 16);   // v_alignbit
        qu[3] = (w1 >> 16) | (w2 << 16);
        qu[5] = (w2 >> 16) | (w3 << 16);
        qu[7] = (w3 >> 16) | (w4 << 16);

#pragma unroll
        for (int k = 0; k < 9; ++k) {
            const int adi = k < 4 ? 4 - k : k - 4;
            const int rm = a > adi ? a : adi;
            const int r0 = rm < 1 ? 1 : rm;           // compile-time
            __half2 qk;
            __builtin_memcpy(&qk, &qu[k], 4);
#pragma unroll
            for (int R = 1; R <= 4; ++R) {
                if (R >= r0)
                    sa2[R - 1] = __hadd2(sa2[R - 1], habs2(__hsub2(qk, m2[R - 1])));
            }
        }
    }

#pragma unroll
    for (int oi = 0; oi < 2; ++oi) {
        const int o = ty * 2 + oi;
#pragma unroll
        for (int R = 1; R <= 4; ++R) {
            const float K = (float)((2 * R + 1) * (2 * R + 1));
            const float sav = oi ? __high2float(sa2[R - 1]) : __low2float(sa2[R - 1]);
            const float homog = __frcp_rn(1.f + sav * (1.f / K));
            __builtin_nontemporal_store((homog + EPS) * EXPM05,
                                        &obase[o * W_ + (R - 1) * 4 * HW + 3 * HW]);
        }
    }
}

extern "C" void kernel_launch(void* const* d_in, const int* in_sizes, int n_in,
                              void* d_out, int out_size, void* d_ws, size_t ws_size,
                              hipStream_t stream) {
    const float* x = (const float*)d_in[0];
    float* out = (float*)d_out;
    dim3 block(64, 8, 1);
    dim3 grid(W_ / 64, H_ / 16, BC);
    texmart_kernel<<<grid, block, 0, stream>>>(x, out);
}

// Round 16
// 38.374 us; speedup vs baseline: 1.0899x; 1.0079x over previous
//
#include <hip/hip_runtime.h>
#include <hip/hip_fp16.h>
#include <math.h>

// Problem constants (fixed by reference setup_inputs): x [2,3,512,512] f32.
#define BC 6
#define H_ 512
#define W_ 512
#define HW (H_ * W_)
#define EPS 1e-6f
#define EXPM05 0.60653065971263342f  // exp(-0.5)

#define TW 72    // tile cols (64 outputs + 8 halo)
#define TH 24    // tile rows (16 outputs + 8 halo)
#define XSS 25   // xs column stride — ODD: b32 lane-bank pattern covers all 32 banks (2/bank, free)
#define XES 13   // xe column stride in uints — ODD for the same reason

// v_pk_max_f16: packed f16 max (no __hmax2 in this ROCm's headers).
static __device__ __forceinline__ __half2 hmax2(__half2 a, __half2 b) {
    __half2 r;
    asm("v_pk_max_f16 %0, %1, %2" : "=v"(r) : "v"(a), "v"(b));
    return r;
}

// Block 64x8 = 512 threads -> 64x16 output tile. 38.6 KB LDS; 4 blocks/CU.
//  A : stage xs (p, f32).                                      [barrier]
//  A2: stage xe[c][t] = half2(row 2t, row 2t+1) from xs (864 units).
//  B : 576 row-pair units; running vertical sums for both rows (10 reads +
//      10 logs per 2 rows), publish all R as packed half2 vh.  [barrier]
//  D : per R: (R+1) aligned ds_read_b64 per stat + hadd2 reduce + parity
//      fix; contrast/energy/entropy out (nontemporal); keep means.
//  E : homogeneity via the ABS-FREE identity  Σ|p-m| = 2(Σmax(p,m) - S1):
//      per contribution just {pk_max, pk_add} (2 ops, was 3) — the -p-m
//      terms fold into the epilogue through the kept means.
// NOTE: no min-occupancy arg in launch_bounds — rounds 4/5 proved it forces
// VGPR=40 + catastrophic scratch spill (FETCH 70-117 MB vs ~6 MB clean).
__global__ __launch_bounds__(512) void texmart_kernel(const float* __restrict__ x,
                                                      float* __restrict__ out) {
    __shared__ float xs[TW][XSS];         // 7200 B  [col][row]
    __shared__ __half2 vh[12][8][72];     // 27648 B [stat*4+R-1][opair][col]
    __shared__ unsigned int xe[TW][XES];  // 3744 B  [col][rowpair] packed half2

    const int tx = threadIdx.x, ty = threadIdx.y;
    const int tid = ty * 64 + tx;
    const int bx = blockIdx.x * 64, by = blockIdx.y * 16;
    const int plane = blockIdx.z;
    const float* __restrict__ xp = x + (size_t)plane * HW;

    // ---------------- A: stage tile (zero pad) ----------------
    for (int idx = tid; idx < TW * TH; idx += 512) {
        const int t = idx / TW, c = idx - t * TW;
        const int gy = by + t - 4, gx = bx + c - 4;
        float v = 0.f;
        if (gy >= 0 && gy < H_ && gx >= 0 && gx < W_) v = xp[gy * W_ + gx];
        xs[c][t] = v;
    }
    __syncthreads();

    // ---------------- A2: pack row-pairs to f16 for E (864 units) ----------------
    // Two explicit b32 reads (NOT float2): with odd XSS, &xs[c][2t] is only
    // 4B-aligned for odd c — a b64 read would be misaligned.
    for (int u = tid; u < TW * 12; u += 512) {
        const int c = u % TW, t = u / TW;          // t = row pair 0..11
        const float p0 = xs[c][2 * t];
        const float p1 = xs[c][2 * t + 1];
        const __half2 h = __float22half2_rn(make_float2(p0, p1));
        unsigned int bits;
        __builtin_memcpy(&bits, &h, 4);
        xe[c][t] = bits;
    }

    // ---------------- B: row-pair vertical running sums, publish all R ----------------
#pragma unroll
    for (int i = 0; i < 2; ++i) {
        if (i == 0 || tid < 64) {            // unit 512+tid handled by wave 0 only
            const int u = tid + i * 512;     // < 576 under guard
            const int op = u / 72, c = u - (u / 72) * 72;
            const float* __restrict__ col = &xs[c][0];
            const float pA = col[2 * op + 4];     // center row of even output row
            const float pB = col[2 * op + 5];     // center row of odd output row
            const float qA = pA * __logf(pA + EPS);
            const float qB = pB * __logf(pB + EPS);
            float s1a = pA, s2a = pA * pA, sla = qA;
            float s1b = pB, s2b = pB * pB, slb = qB;
            float lop = pA, hip = pB, qlop = qA, qhip = qB;   // lo_{R-1}, hi_{R-1}
#pragma unroll
            for (int R = 1; R <= 4; ++R) {
                const float lo = col[2 * op + 4 - R];
                const float hi = col[2 * op + 5 + R];
                const float qlo = lo * __logf(lo + EPS);      // zero-pad -> exactly 0
                const float qhi = hi * __logf(hi + EPS);
                // row A window rows [2op+4-R, 2op+4+R]; row 2op+4+R == hi_{R-1}
                s1a += lo + hip;
                s2a = __fmaf_rn(lo, lo, __fmaf_rn(hip, hip, s2a));
                sla += qlo + qhip;
                // row B window rows [2op+5-R, 2op+5+R]; row 2op+5-R == lo_{R-1}
                s1b += lop + hi;
                s2b = __fmaf_rn(lop, lop, __fmaf_rn(hi, hi, s2b));
                slb += qlop + qhi;
                vh[0 * 4 + R - 1][op][c] = __float22half2_rn(make_float2(s1a, s1b));
                vh[1 * 4 + R - 1][op][c] = __float22half2_rn(make_float2(s2a, s2b));
                vh[2 * 4 + R - 1][op][c] = __float22half2_rn(make_float2(sla, slb));
                lop = lo; hip = hi; qlop = qlo; qhip = qhi;
            }
        }
    }
    __syncthreads();

    // ---------------- D: per-R horizontal sums via aligned b64 + parity fix ----------------
    float mean[2][4];
    const int gxx = bx + tx;
    float* __restrict__ obase = out + (size_t)plane * 16 * HW + (size_t)by * W_ + gxx;

#pragma unroll
    for (int R = 1; R <= 4; ++R) {
        // span words [tx+4-R, tx+4+R]; aligned start a (even) -> R+1 b64 loads
        // cover span plus ONE surplus column (front if tx+4-R odd, else back).
        const int a = (tx + 4 - R) & ~1;
        const bool frontX = ((tx + 4 - R) & 1) != 0;
        __half2 S[3];
#pragma unroll
        for (int st = 0; st < 3; ++st) {
            const __half2* __restrict__ row = &vh[st * 4 + (R - 1)][ty][0];
            __half2 acc = __float2half2_rn(0.f);
            __half2 first = __float2half2_rn(0.f), last = __float2half2_rn(0.f);
#pragma unroll
            for (int k = 0; k <= R; ++k) {
                const uint2 u = *(const uint2*)&row[a + 2 * k];   // ds_read_b64 (8B aligned)
                const __half2 lo = *(const __half2*)&u.x;
                const __half2 hi = *(const __half2*)&u.y;
                if (k == 0) first = lo;
                if (k == R) last = hi;
                acc = __hadd2(acc, __hadd2(lo, hi));
            }
            S[st] = __hsub2(acc, frontX ? first : last);
        }
        const float S1v[2] = {__low2float(S[0]), __high2float(S[0])};
        const float S2v[2] = {__low2float(S[1]), __high2float(S[1])};
        const float SLv[2] = {__low2float(S[2]), __high2float(S[2])};

        const float K = (float)((2 * R + 1) * (2 * R + 1));
        const float invK = 1.f / K;
        const float invKm1 = 1.f / (K - 1.f);
#pragma unroll
        for (int oi = 0; oi < 2; ++oi) {
            const int o = ty * 2 + oi;
            const float m = S1v[oi] * invK;
            mean[oi][R - 1] = m;
            float S2c = __fmaf_rn(-S1v[oi], m, S2v[oi]);   // Σ(p-mean)^2
            if (S2c < 0.f) S2c = 0.f;
            const float sd = sqrtf(S2c * invKm1) + EPS;    // ddof=1 std + EPS
            const float contrast = (S2c * invK) * __frcp_rn(sd * sd);
            const float energy = S2v[oi] * invK;
            const float entropy = -SLv[oi] * invK;

            float* __restrict__ o4 = obase + o * W_ + (R - 1) * 4 * HW;
            __builtin_nontemporal_store((contrast + EPS) * EXPM05, &o4[0 * HW]);
            __builtin_nontemporal_store((energy + EPS) * EXPM05, &o4[1 * HW]);
            __builtin_nontemporal_store((entropy + EPS) * EXPM05, &o4[2 * HW]);
        }
    }

    // ---------------- E: homogeneity, abs-free (max identity), f16-packed ----------------
    // Σ_w |p - m_R| = 2(Σ_w max(p, m_R) - S1_R); accumulate only Σmax.
    __half2 m2[4];
#pragma unroll
    for (int R = 0; R < 4; ++R)
        m2[R] = __float22half2_rn(make_float2(mean[0][R], mean[1][R]));

    __half2 sx2[4];
#pragma unroll
    for (int R = 0; R < 4; ++R) sx2[R] = __float2half2_rn(0.f);

#pragma unroll
    for (int dj = 0; dj < 9; ++dj) {
        const int a = dj < 4 ? 4 - dj : dj - 4;
        const unsigned int* __restrict__ col = &xe[tx + dj][ty];  // pairs ty..ty+4
        const unsigned int w0 = col[0], w1 = col[1], w2 = col[2], w3 = col[3], w4 = col[4];
        unsigned int qu[9];
        qu[0] = w0; qu[2] = w1; qu[4] = w2; qu[6] = w3; qu[8] = w4;
        qu[1] = (w0 >> 16) | (w1 << 16);   // v_alignbit
        qu[3] = (w1 >> 16) | (w2 << 16);
        qu[5] = (w2 >> 16) | (w3 << 16);
        qu[7] = (w3 >> 16) | (w4 << 16);

#pragma unroll
        for (int k = 0; k < 9; ++k) {
            const int adi = k < 4 ? 4 - k : k - 4;
            const int rm = a > adi ? a : adi;
            const int r0 = rm < 1 ? 1 : rm;           // compile-time
            __half2 qk;
            __builtin_memcpy(&qk, &qu[k], 4);
#pragma unroll
            for (int R = 1; R <= 4; ++R) {
                if (R >= r0)
                    sx2[R - 1] = __hadd2(sx2[R - 1], hmax2(qk, m2[R - 1]));
            }
        }
    }

#pragma unroll
    for (int oi = 0; oi < 2; ++oi) {
        const int o = ty * 2 + oi;
#pragma unroll
        for (int R = 1; R <= 4; ++R) {
            const float K = (float)((2 * R + 1) * (2 * R + 1));
            const float sxv = oi ? __high2float(sx2[R - 1]) : __low2float(sx2[R - 1]);
            float meanad = 2.f * __fmaf_rn(sxv, 1.f / K, -mean[oi][R - 1]);  // mean|p-m|
            if (meanad < 0.f) meanad = 0.f;           // guard f16 cancellation
            const float homog = __frcp_rn(1.f + meanad);
            __builtin_nontemporal_store((homog + EPS) * EXPM05,
                                        &obase[o * W_ + (R - 1) * 4 * HW + 3 * HW]);
        }
    }
}

extern "C" void kernel_launch(void* const* d_in, const int* in_sizes, int n_in,
                              void* d_out, int out_size, void* d_ws, size_t ws_size,
                              hipStream_t stream) {
    const float* x = (const float*)d_in[0];
    float* out = (float*)d_out;
    dim3 block(64, 8, 1);
    dim3 grid(W_ / 64, H_ / 16, BC);
    texmart_kernel<<<grid, block, 0, stream>>>(x, out);
}